// Round 8
// baseline (155.928 us; speedup 1.0000x reference)
//
#include <hip/hip_runtime.h>

#define L2E 1.4426950408889634f

// ---------------- Wsum: wsum[h] = sum_n W[h][n] ----------------
__global__ __launch_bounds__(256) void wsum_kernel(const float* __restrict__ W,
                                                   float* __restrict__ wsum) {
    int wave = threadIdx.x >> 6, lane = threadIdx.x & 63;
    int h = blockIdx.x * 4 + wave;            // grid 64 -> h in [0,256)
    const float* row = W + (size_t)h * 1024;
    float s = 0.f;
#pragma unroll
    for (int i = 0; i < 16; ++i) s += row[lane + 64 * i];
#pragma unroll
    for (int off = 32; off; off >>= 1) s += __shfl_xor(s, off, 64);
    if (lane == 0) wsum[h] = s;
}

// ------- prep: covT0[j][k] = cov[k][j] (diag->0); clT[j][k] = {cov0, ld0} ----
__global__ __launch_bounds__(256) void prep_kernel(const float* __restrict__ cov,
                                                   const float* __restrict__ ld,
                                                   float* __restrict__ covT0,
                                                   float2* __restrict__ clT) {
    __shared__ float tc[32][33];
    __shared__ float tl[32][33];
    const int bx = blockIdx.x * 32, by = blockIdx.y * 32;
    const int x = threadIdx.x & 31;
    const int y = threadIdx.x >> 5;           // 0..7
#pragma unroll
    for (int i = 0; i < 32; i += 8) {
        int r = by + y + i, c = bx + x;
        float cv = cov[(size_t)r * 256 + c];
        float lv = ld[(size_t)r * 256 + c];
        if (r == c) { cv = 0.f; lv = 0.f; }
        tc[y + i][x] = cv; tl[y + i][x] = lv;
    }
    __syncthreads();
#pragma unroll
    for (int i = 0; i < 32; i += 8) {
        int r = bx + y + i, c = by + x;
        float cv = tc[x][y + i], lv = tl[x][y + i];
        covT0[(size_t)r * 256 + c] = cv;
        clT[(size_t)r * 256 + c] = make_float2(cv, lv);
    }
}

// ---------------- GEMM: C[8192,256] = X[8192,1024] @ W[256,1024]^T ----------
// rows of C alternate: row 2b = values, row 2b+1 = mask
#define GBK 32
#define LDT 68

__global__ __launch_bounds__(256) void gemm_kernel(const float* __restrict__ X,
                                                   const float* __restrict__ W,
                                                   float* __restrict__ C) {
    __shared__ float As[2][GBK][LDT];
    __shared__ float Bs[2][GBK][LDT];
    const int tid = threadIdx.x;
    const int row = tid >> 2;                 // 0..63
    const int k0  = (tid & 3) << 3;           // 0,8,16,24
    const int gm0 = blockIdx.x * 64;
    const int gn0 = blockIdx.y * 64;
    const int tx = tid & 15, ty = tid >> 4;
    float acc[4][4] = {};
    const float* Xp = X + (size_t)(gm0 + row) * 1024 + k0;
    const float* Wp = W + (size_t)(gn0 + row) * 1024 + k0;

    float4 xa = *(const float4*)(Xp);
    float4 xb = *(const float4*)(Xp + 4);
    float4 wa = *(const float4*)(Wp);
    float4 wb = *(const float4*)(Wp + 4);

#define WRBUF(B)                                                        \
    {                                                                   \
        As[B][k0 + 0][row] = xa.x; As[B][k0 + 1][row] = xa.y;           \
        As[B][k0 + 2][row] = xa.z; As[B][k0 + 3][row] = xa.w;           \
        As[B][k0 + 4][row] = xb.x; As[B][k0 + 5][row] = xb.y;           \
        As[B][k0 + 6][row] = xb.z; As[B][k0 + 7][row] = xb.w;           \
        Bs[B][k0 + 0][row] = wa.x; Bs[B][k0 + 1][row] = wa.y;           \
        Bs[B][k0 + 2][row] = wa.z; Bs[B][k0 + 3][row] = wa.w;           \
        Bs[B][k0 + 4][row] = wb.x; Bs[B][k0 + 5][row] = wb.y;           \
        Bs[B][k0 + 6][row] = wb.z; Bs[B][k0 + 7][row] = wb.w;           \
    }

    WRBUF(0);
    xa = *(const float4*)(Xp + GBK);
    xb = *(const float4*)(Xp + GBK + 4);
    wa = *(const float4*)(Wp + GBK);
    wb = *(const float4*)(Wp + GBK + 4);
    __syncthreads();

    int cur = 0;
    for (int it = 0; it < 32; ++it) {
        if (it < 31) {                        // write tile it+1 into other buffer
            if (cur == 0) WRBUF(1) else WRBUF(0);
        }
        if (it < 30) {                        // prefetch tile it+2 into regs
            int off = (it + 2) * GBK;
            xa = *(const float4*)(Xp + off);
            xb = *(const float4*)(Xp + off + 4);
            wa = *(const float4*)(Wp + off);
            wb = *(const float4*)(Wp + off + 4);
        }
#pragma unroll
        for (int kk = 0; kk < GBK; ++kk) {
            float4 av = *(const float4*)&As[cur][kk][ty << 2];
            float4 bv = *(const float4*)&Bs[cur][kk][tx << 2];
            float am[4] = {av.x, av.y, av.z, av.w};
            float bn[4] = {bv.x, bv.y, bv.z, bv.w};
#pragma unroll
            for (int i = 0; i < 4; ++i)
#pragma unroll
                for (int j = 0; j < 4; ++j)
                    acc[i][j] = __builtin_fmaf(am[i], bn[j], acc[i][j]);
        }
        __syncthreads();
        cur ^= 1;
    }
#pragma unroll
    for (int i = 0; i < 4; ++i) {
        float4 o = {acc[i][0], acc[i][1], acc[i][2], acc[i][3]};
        *(float4*)(C + (size_t)(gm0 + (ty << 2) + i) * 256 + gn0 + (tx << 2)) = o;
    }
#undef WRBUF
}

// ---------------- Head: thread-per-(b,k), zero-diag operands ----------------
// off-diag r_j = mk * p_j, p_j = cov0[k][j]*omm[b][j];  r_kk = 1 + mk*p_kk.
// pass1 (cov0): sp = sum_{j!=k} p; pmax/pmin over p (spurious 0 candidate is
// safe: sum_j w_j = 1 => max w >= 1/256 > 0).  mx = exact max of corrected w.
// pass2 (cov0,ld0): e = exp2(fma(p,c1,c0)); diag contributes exp2(c0) to se
// (subtracted in epilogue) and 0 to dp (ld diag zeroed).
#define NB 4

__global__ __launch_bounds__(256) void head_kernel(const float* __restrict__ C,
                                                   const float* __restrict__ wsum,
                                                   const float* __restrict__ covT0,
                                                   const float2* __restrict__ clT,
                                                   const float* __restrict__ cov,
                                                   const float* __restrict__ ld,
                                                   float* __restrict__ out) {
    __shared__ float  omm[NB][256];
    __shared__ float2 pv[NB][256];            // {omm, values}
    const int k = threadIdx.x;
    const int b0 = blockIdx.x * NB;

    const float ws = wsum[k];
    const float cdiag = cov[(size_t)k * 257];
    const float ldiag = ld[(size_t)k * 257];

    float mk[NB], vak[NB], omk[NB], sp[NB], pmax[NB], pmin[NB];
#pragma unroll
    for (int b = 0; b < NB; ++b) {
        float va = C[(size_t)(2 * (b0 + b)) * 256 + k];
        float ms = C[(size_t)(2 * (b0 + b) + 1) * 256 + k];
        float o  = ws - ms;
        mk[b] = ms; vak[b] = va; omk[b] = o;
        omm[b][k] = o;
        pv[b][k] = make_float2(o, va);
        sp[b] = 0.f; pmax[b] = 0.f; pmin[b] = 0.f;
    }
    __syncthreads();

    // ---- pass 1: off-diag row sum + extrema of p (no branches) ----
#pragma unroll 8
    for (int j = 0; j < 256; ++j) {
        float cv = covT0[j * 256 + k];
#pragma unroll
        for (int b = 0; b < NB; ++b) {
            float p = cv * omm[b][j];
            sp[b]   += p;
            pmax[b]  = fmaxf(pmax[b], p);
            pmin[b]  = fminf(pmin[b], p);
        }
    }

    // ---- per-b softmax constants (exact corrected max) ----
    float c1[NB], c0[NB], ek[NB], se[NB], dp[NB];
#pragma unroll
    for (int b = 0; b < NB; ++b) {
        float m   = mk[b];
        float pkk = cdiag * omk[b];
        float rkk = __builtin_fmaf(m, pkk, 1.0f);
        float sum = __builtin_fmaf(m, sp[b] + pkk, 1.0f);
        float iv  = __builtin_amdgcn_rcpf(sum);
        float rmax = (m >= 0.f) ? m * pmax[b] : m * pmin[b];
        float rmin = (m >= 0.f) ? m * pmin[b] : m * pmax[b];
        rmax = fmaxf(rmax, rkk);
        rmin = fminf(rmin, rkk);
        float mx = (iv >= 0.f) ? iv * rmax : iv * rmin;   // == max_j w_j
        c1[b] = m * iv * L2E;
        c0[b] = -mx * L2E;
        ek[b] = __builtin_amdgcn_exp2f(__builtin_fmaf(rkk * iv, L2E, c0[b]));
        se[b] = 0.f; dp[b] = 0.f;
    }

    // ---- pass 2: exp + weighted dot over zero-diag arrays ----
#pragma unroll 8
    for (int j = 0; j < 256; ++j) {
        float2 cl = clT[j * 256 + k];
#pragma unroll
        for (int b = 0; b < NB; ++b) {
            float2 ov = pv[b][j];
            float p = cl.x * ov.x;
            float e = __builtin_amdgcn_exp2f(__builtin_fmaf(p, c1[b], c0[b]));
            se[b] += e;
            dp[b]  = __builtin_fmaf(e, cl.y * ov.y, dp[b]);
        }
    }

    // ---- epilogue: swap spurious diag exp for the true one ----
#pragma unroll
    for (int b = 0; b < NB; ++b) {
        float espur = __builtin_amdgcn_exp2f(c0[b]);
        float sef = se[b] + (ek[b] - espur);
        float dpf = __builtin_fmaf(ek[b], ldiag * vak[b], dp[b]);
        out[(size_t)(b0 + b) * 256 + k] = dpf * __builtin_amdgcn_rcpf(sef);
    }
}

extern "C" void kernel_launch(void* const* d_in, const int* in_sizes, int n_in,
                              void* d_out, int out_size, void* d_ws, size_t ws_size,
                              hipStream_t stream) {
    const float* x    = (const float*)d_in[0];   // [4096,2,1024]
    const float* W    = (const float*)d_in[1];   // [256,1024]
    const float* cov  = (const float*)d_in[2];   // [256,256]
    const float* ldng = (const float*)d_in[3];   // [256,256]
    float* out = (float*)d_out;                  // [4096,256]

    float*  C     = (float*)d_ws;                        // [8192,256]
    float*  wsum  = C + (size_t)8192 * 256;              // [256]
    float*  covT0 = wsum + 256;                          // [256,256], diag 0
    float2* clT   = (float2*)(covT0 + 65536);            // [256,256] {cov0,ld0}

    wsum_kernel<<<64, 256, 0, stream>>>(W, wsum);
    prep_kernel<<<dim3(8, 8), 256, 0, stream>>>(cov, ldng, covT0, clT);
    gemm_kernel<<<dim3(128, 4), 256, 0, stream>>>(x, W, C);
    head_kernel<<<1024, 256, 0, stream>>>(C, wsum, covT0, clT, cov, ldng, out);
}

// Round 9
// 146.799 us; speedup vs baseline: 1.0622x; 1.0622x over previous
//
#include <hip/hip_runtime.h>

#define L2E 1.4426950408889634f

// ---------------- Wsum: wsum[h] = sum_n W[h][n] ----------------
__global__ __launch_bounds__(256) void wsum_kernel(const float* __restrict__ W,
                                                   float* __restrict__ wsum) {
    int wave = threadIdx.x >> 6, lane = threadIdx.x & 63;
    int h = blockIdx.x * 4 + wave;            // grid 64 -> h in [0,256)
    const float* row = W + (size_t)h * 1024;
    float s = 0.f;
#pragma unroll
    for (int i = 0; i < 16; ++i) s += row[lane + 64 * i];
#pragma unroll
    for (int off = 32; off; off >>= 1) s += __shfl_xor(s, off, 64);
    if (lane == 0) wsum[h] = s;
}

// ------- prep: covT0[j][k] = cov[k][j] (diag->0); clT[j][k] = {cov0, ld0} ----
__global__ __launch_bounds__(256) void prep_kernel(const float* __restrict__ cov,
                                                   const float* __restrict__ ld,
                                                   float* __restrict__ covT0,
                                                   float2* __restrict__ clT) {
    __shared__ float tc[32][33];
    __shared__ float tl[32][33];
    const int bx = blockIdx.x * 32, by = blockIdx.y * 32;
    const int x = threadIdx.x & 31;
    const int y = threadIdx.x >> 5;           // 0..7
#pragma unroll
    for (int i = 0; i < 32; i += 8) {
        int r = by + y + i, c = bx + x;
        float cv = cov[(size_t)r * 256 + c];
        float lv = ld[(size_t)r * 256 + c];
        if (r == c) { cv = 0.f; lv = 0.f; }
        tc[y + i][x] = cv; tl[y + i][x] = lv;
    }
    __syncthreads();
#pragma unroll
    for (int i = 0; i < 32; i += 8) {
        int r = bx + y + i, c = by + x;
        float cv = tc[x][y + i], lv = tl[x][y + i];
        covT0[(size_t)r * 256 + c] = cv;
        clT[(size_t)r * 256 + c] = make_float2(cv, lv);
    }
}

// ---------------- GEMM (R5 version): C[8192,256] = X @ W^T ------------------
// rows of C alternate: row 2b = values, row 2b+1 = mask
#define BK 16
#define LDT 68

__global__ __launch_bounds__(256) void gemm_kernel(const float* __restrict__ X,
                                                   const float* __restrict__ W,
                                                   float* __restrict__ C) {
    __shared__ float As[BK][LDT];
    __shared__ float Bs[BK][LDT];
    const int tid = threadIdx.x;
    const int row = tid >> 2;
    const int c4  = (tid & 3) << 2;
    const int gm0 = blockIdx.x * 64;
    const int gn0 = blockIdx.y * 64;
    const int tx = tid & 15, ty = tid >> 4;
    float acc[4][4] = {};
    const float* Xp = X + (size_t)(gm0 + row) * 1024 + c4;
    const float* Wp = W + (size_t)(gn0 + row) * 1024 + c4;

    float4 a = *(const float4*)(Xp);
    float4 b = *(const float4*)(Wp);
    for (int kt = 0; kt < 1024; kt += BK) {
        __syncthreads();
        As[c4 + 0][row] = a.x; As[c4 + 1][row] = a.y;
        As[c4 + 2][row] = a.z; As[c4 + 3][row] = a.w;
        Bs[c4 + 0][row] = b.x; Bs[c4 + 1][row] = b.y;
        Bs[c4 + 2][row] = b.z; Bs[c4 + 3][row] = b.w;
        __syncthreads();
        if (kt + BK < 1024) {                 // prefetch next tile into regs
            a = *(const float4*)(Xp + kt + BK);
            b = *(const float4*)(Wp + kt + BK);
        }
#pragma unroll
        for (int kk = 0; kk < BK; ++kk) {
            float4 av = *(const float4*)&As[kk][ty << 2];
            float4 bv = *(const float4*)&Bs[kk][tx << 2];
            float am[4] = {av.x, av.y, av.z, av.w};
            float bn[4] = {bv.x, bv.y, bv.z, bv.w};
#pragma unroll
            for (int i = 0; i < 4; ++i)
#pragma unroll
                for (int j = 0; j < 4; ++j)
                    acc[i][j] = __builtin_fmaf(am[i], bn[j], acc[i][j]);
        }
    }
#pragma unroll
    for (int i = 0; i < 4; ++i) {
        float4 o = {acc[i][0], acc[i][1], acc[i][2], acc[i][3]};
        *(float4*)(C + (size_t)(gm0 + (ty << 2) + i) * 256 + gn0 + (tx << 2)) = o;
    }
}

// ---------------- Head: thread-per-(b,k), b-interleaved LDS -----------------
// off-diag r_j = mk * p_j, p_j = cov0[k][j]*omm[b][j];  r_kk = 1 + mk*p_kk.
// pass1 (cov0): sp = sum_{j!=k} p; pmax/pmin over p (spurious 0 is safe:
// sum_j w_j = 1 => max w >= 1/256 > 0).  mx = exact max of corrected w.
// pass2 (cov0,ld0): e = exp2(fma(p,c1,c0)); diag contributes exp2(c0) to se
// (swapped for true diag term in epilogue; ld diag zeroed keeps dp clean).
// LDS: omI[j] = {omm[b0..b0+3][j]}, vaI[j] = {values[b0..b0+3][j]} ->
// one broadcast ds_read_b128 feeds all 4 b's per pass per j.
#define NB 4

__global__ __launch_bounds__(256) void head_kernel(const float* __restrict__ C,
                                                   const float* __restrict__ wsum,
                                                   const float* __restrict__ covT0,
                                                   const float2* __restrict__ clT,
                                                   const float* __restrict__ cov,
                                                   const float* __restrict__ ld,
                                                   float* __restrict__ out) {
    __shared__ float4 omI[256];
    __shared__ float4 vaI[256];
    const int k = threadIdx.x;
    const int b0 = blockIdx.x * NB;

    const float ws = wsum[k];
    const float cdiag = cov[(size_t)k * 257];
    const float ldiag = ld[(size_t)k * 257];

    float mk[NB], vak[NB], omk[NB], sp[NB], pmax[NB], pmin[NB];
#pragma unroll
    for (int b = 0; b < NB; ++b) {
        float va = C[(size_t)(2 * (b0 + b)) * 256 + k];
        float ms = C[(size_t)(2 * (b0 + b) + 1) * 256 + k];
        float o  = ws - ms;
        mk[b] = ms; vak[b] = va; omk[b] = o;
        ((float*)&omI[k])[b] = o;
        ((float*)&vaI[k])[b] = va;
        sp[b] = 0.f; pmax[b] = 0.f; pmin[b] = 0.f;
    }
    __syncthreads();

    // ---- pass 1: off-diag row sum + exact extrema of p ----
#pragma unroll 8
    for (int j = 0; j < 256; ++j) {
        float cv = covT0[j * 256 + k];
        float4 om = omI[j];
        float omv[4] = {om.x, om.y, om.z, om.w};
#pragma unroll
        for (int b = 0; b < NB; ++b) {
            float p = cv * omv[b];
            sp[b]   += p;
            pmax[b]  = fmaxf(pmax[b], p);
            pmin[b]  = fminf(pmin[b], p);
        }
    }

    // ---- per-b softmax constants (exact corrected max) ----
    float c1[NB], c0[NB], ek[NB], se[NB], dp[NB];
#pragma unroll
    for (int b = 0; b < NB; ++b) {
        float m   = mk[b];
        float pkk = cdiag * omk[b];
        float rkk = __builtin_fmaf(m, pkk, 1.0f);
        float sum = __builtin_fmaf(m, sp[b] + pkk, 1.0f);
        float iv  = __builtin_amdgcn_rcpf(sum);
        float rmax = (m >= 0.f) ? m * pmax[b] : m * pmin[b];
        float rmin = (m >= 0.f) ? m * pmin[b] : m * pmax[b];
        rmax = fmaxf(rmax, rkk);
        rmin = fminf(rmin, rkk);
        float mx = (iv >= 0.f) ? iv * rmax : iv * rmin;   // == max_j w_j
        c1[b] = m * iv * L2E;
        c0[b] = -mx * L2E;
        ek[b] = __builtin_amdgcn_exp2f(__builtin_fmaf(rkk * iv, L2E, c0[b]));
        se[b] = 0.f; dp[b] = 0.f;
    }

    // ---- pass 2: exp + weighted dot over zero-diag arrays ----
#pragma unroll 8
    for (int j = 0; j < 256; ++j) {
        float2 cl = clT[j * 256 + k];
        float4 om = omI[j];
        float4 va = vaI[j];
        float omv[4] = {om.x, om.y, om.z, om.w};
        float vav[4] = {va.x, va.y, va.z, va.w};
#pragma unroll
        for (int b = 0; b < NB; ++b) {
            float p = cl.x * omv[b];
            float e = __builtin_amdgcn_exp2f(__builtin_fmaf(p, c1[b], c0[b]));
            se[b] += e;
            dp[b]  = __builtin_fmaf(e, cl.y * vav[b], dp[b]);
        }
    }

    // ---- epilogue: swap spurious diag exp for the true one ----
#pragma unroll
    for (int b = 0; b < NB; ++b) {
        float espur = __builtin_amdgcn_exp2f(c0[b]);
        float sef = se[b] + (ek[b] - espur);
        float dpf = __builtin_fmaf(ek[b], ldiag * vak[b], dp[b]);
        out[(size_t)(b0 + b) * 256 + k] = dpf * __builtin_amdgcn_rcpf(sef);
    }
}

extern "C" void kernel_launch(void* const* d_in, const int* in_sizes, int n_in,
                              void* d_out, int out_size, void* d_ws, size_t ws_size,
                              hipStream_t stream) {
    const float* x    = (const float*)d_in[0];   // [4096,2,1024]
    const float* W    = (const float*)d_in[1];   // [256,1024]
    const float* cov  = (const float*)d_in[2];   // [256,256]
    const float* ldng = (const float*)d_in[3];   // [256,256]
    float* out = (float*)d_out;                  // [4096,256]

    float*  C     = (float*)d_ws;                        // [8192,256]
    float*  wsum  = C + (size_t)8192 * 256;              // [256]
    float*  covT0 = wsum + 256;                          // [256,256], diag 0
    float2* clT   = (float2*)(covT0 + 65536);            // [256,256] {cov0,ld0}

    wsum_kernel<<<64, 256, 0, stream>>>(W, wsum);
    prep_kernel<<<dim3(8, 8), 256, 0, stream>>>(cov, ldng, covT0, clT);
    gemm_kernel<<<dim3(128, 4), 256, 0, stream>>>(x, W, C);
    head_kernel<<<1024, 256, 0, stream>>>(C, wsum, covT0, clT, cov, ldng, out);
}

// Round 13
// 146.360 us; speedup vs baseline: 1.0654x; 1.0030x over previous
//
#include <hip/hip_runtime.h>

#define L2E 1.4426950408889634f

// ---------------- Wsum: wsum[h] = sum_n W[h][n] ----------------
__global__ __launch_bounds__(256) void wsum_kernel(const float* __restrict__ W,
                                                   float* __restrict__ wsum) {
    int wave = threadIdx.x >> 6, lane = threadIdx.x & 63;
    int h = blockIdx.x * 4 + wave;            // grid 64 -> h in [0,256)
    const float* row = W + (size_t)h * 1024;
    float s = 0.f;
#pragma unroll
    for (int i = 0; i < 16; ++i) s += row[lane + 64 * i];
#pragma unroll
    for (int off = 32; off; off >>= 1) s += __shfl_xor(s, off, 64);
    if (lane == 0) wsum[h] = s;
}

// ------- prep: pair-major zero-diag transposed tables -----------------------
// covP[jp*256+k] = {cov0T[2jp][k], cov0T[2jp+1][k]}   (cov0T[j][k]=cov[k][j], diag 0)
// clP [jp*256+k] = {cov0T[2jp][k], ld0T[2jp][k], cov0T[2jp+1][k], ld0T[2jp+1][k]}
__global__ __launch_bounds__(256) void prep_kernel(const float* __restrict__ cov,
                                                   const float* __restrict__ ld,
                                                   float2* __restrict__ covP,
                                                   float4* __restrict__ clP) {
    __shared__ float tc[32][33];
    __shared__ float tl[32][33];
    const int bx = blockIdx.x * 32, by = blockIdx.y * 32;   // bx: j block, by: k block
    const int x = threadIdx.x & 31;
    const int y = threadIdx.x >> 5;           // 0..7
#pragma unroll
    for (int i = 0; i < 32; i += 8) {
        int r = by + y + i, c = bx + x;       // r = k (cov row), c = j
        float cv = cov[(size_t)r * 256 + c];
        float lv = ld[(size_t)r * 256 + c];
        if (r == c) { cv = 0.f; lv = 0.f; }
        tc[y + i][x] = cv; tl[y + i][x] = lv; // tc[k-in-blk][j-in-blk]
    }
    __syncthreads();
    const int k = by + x;
#pragma unroll
    for (int i2 = 0; i2 < 16; i2 += 8) {
        int y2 = y + i2;                      // pair index within j-block, 0..15
        int jp = (bx >> 1) + y2;
        float c0 = tc[x][2 * y2],     l0 = tl[x][2 * y2];
        float c1 = tc[x][2 * y2 + 1], l1 = tl[x][2 * y2 + 1];
        covP[(size_t)jp * 256 + k] = make_float2(c0, c1);
        clP[(size_t)jp * 256 + k]  = make_float4(c0, l0, c1, l1);
    }
}

// ---------------- GEMM (R5 version, proven): C[8192,256] = X @ W^T ----------
// rows of C alternate: row 2b = values, row 2b+1 = mask
#define BK 16
#define LDT 68

__global__ __launch_bounds__(256) void gemm_kernel(const float* __restrict__ X,
                                                   const float* __restrict__ W,
                                                   float* __restrict__ C) {
    __shared__ float As[BK][LDT];
    __shared__ float Bs[BK][LDT];
    const int tid = threadIdx.x;
    const int row = tid >> 2;
    const int c4  = (tid & 3) << 2;
    const int gm0 = blockIdx.x * 64;
    const int gn0 = blockIdx.y * 64;
    const int tx = tid & 15, ty = tid >> 4;
    float acc[4][4] = {};
    const float* Xp = X + (size_t)(gm0 + row) * 1024 + c4;
    const float* Wp = W + (size_t)(gn0 + row) * 1024 + c4;

    float4 a = *(const float4*)(Xp);
    float4 b = *(const float4*)(Wp);
    for (int kt = 0; kt < 1024; kt += BK) {
        __syncthreads();
        As[c4 + 0][row] = a.x; As[c4 + 1][row] = a.y;
        As[c4 + 2][row] = a.z; As[c4 + 3][row] = a.w;
        Bs[c4 + 0][row] = b.x; Bs[c4 + 1][row] = b.y;
        Bs[c4 + 2][row] = b.z; Bs[c4 + 3][row] = b.w;
        __syncthreads();
        if (kt + BK < 1024) {                 // prefetch next tile into regs
            a = *(const float4*)(Xp + kt + BK);
            b = *(const float4*)(Wp + kt + BK);
        }
#pragma unroll
        for (int kk = 0; kk < BK; ++kk) {
            float4 av = *(const float4*)&As[kk][ty << 2];
            float4 bv = *(const float4*)&Bs[kk][tx << 2];
            float am[4] = {av.x, av.y, av.z, av.w};
            float bn[4] = {bv.x, bv.y, bv.z, bv.w};
#pragma unroll
            for (int i = 0; i < 4; ++i)
#pragma unroll
                for (int j = 0; j < 4; ++j)
                    acc[i][j] = __builtin_fmaf(am[i], bn[j], acc[i][j]);
        }
    }
#pragma unroll
    for (int i = 0; i < 4; ++i) {
        float4 o = {acc[i][0], acc[i][1], acc[i][2], acc[i][3]};
        *(float4*)(C + (size_t)(gm0 + (ty << 2) + i) * 256 + gn0 + (tx << 2)) = o;
    }
}

// ---------------- Head: thread-per-(b,k), paired-j scalar math --------------
// off-diag r_j = mk*p_j, p_j = cov0[k][j]*omm[b][j];  r_kk = 1 + mk*p_kk.
// pass1 (covP): sp = sum_{j!=k} p; exact pmax/pmin (spurious 0 at j==k safe:
// sum_j w_j = 1 => max w >= 1/256 > 0). mx = exact max of corrected w.
// pass2 (clP): e = exp2(fma(p,c1,c0)); spurious diag exp2(c0) swapped for the
// true diag term in epilogue (ld diag zeroed keeps dp clean).
#define NB 4

__global__ __launch_bounds__(256) void head_kernel(const float* __restrict__ C,
                                                   const float* __restrict__ wsum,
                                                   const float2* __restrict__ covP,
                                                   const float4* __restrict__ clP,
                                                   const float* __restrict__ cov,
                                                   const float* __restrict__ ld,
                                                   float* __restrict__ out) {
    __shared__ float4 omI[256];
    __shared__ float4 vaI[256];
    const int k = threadIdx.x;
    const int b0 = blockIdx.x * NB;

    const float ws = wsum[k];
    const float cdiag = cov[(size_t)k * 257];
    const float ldiag = ld[(size_t)k * 257];

    float mk[NB], vak[NB], omk[NB], sp[NB], pmax[NB], pmin[NB];
#pragma unroll
    for (int b = 0; b < NB; ++b) {
        float va = C[(size_t)(2 * (b0 + b)) * 256 + k];
        float ms = C[(size_t)(2 * (b0 + b) + 1) * 256 + k];
        float o  = ws - ms;
        mk[b] = ms; vak[b] = va; omk[b] = o;
        ((float*)&omI[k])[b] = o;
        ((float*)&vaI[k])[b] = va;
        sp[b] = 0.f; pmax[b] = 0.f; pmin[b] = 0.f;
    }
    __syncthreads();

    const float2* cp = covP + k;

    // ---- pass 1: off-diag row sum + exact extrema, 2 j per iter ----
#pragma unroll 4
    for (int jp = 0; jp < 128; ++jp) {
        float2 cv = cp[(size_t)jp * 256];
        float4 om0 = omI[2 * jp];
        float4 om1 = omI[2 * jp + 1];
        float o0[4] = {om0.x, om0.y, om0.z, om0.w};
        float o1[4] = {om1.x, om1.y, om1.z, om1.w};
#pragma unroll
        for (int b = 0; b < NB; ++b) {
            float p0 = cv.x * o0[b];
            float p1 = cv.y * o1[b];
            sp[b]  += p0 + p1;
            pmax[b] = fmaxf(fmaxf(pmax[b], p0), p1);   // v_max3
            pmin[b] = fminf(fminf(pmin[b], p0), p1);   // v_min3
        }
    }

    // ---- per-b softmax constants (exact corrected max) ----
    float c1[NB], c0[NB], ek[NB], se[NB], dp[NB];
#pragma unroll
    for (int b = 0; b < NB; ++b) {
        float m   = mk[b];
        float pkk = cdiag * omk[b];
        float rkk = __builtin_fmaf(m, pkk, 1.0f);
        float sum = __builtin_fmaf(m, sp[b] + pkk, 1.0f);
        float iv  = __builtin_amdgcn_rcpf(sum);
        float rmax = (m >= 0.f) ? m * pmax[b] : m * pmin[b];
        float rmin = (m >= 0.f) ? m * pmin[b] : m * pmax[b];
        rmax = fmaxf(rmax, rkk);
        rmin = fminf(rmin, rkk);
        float mx = (iv >= 0.f) ? iv * rmax : iv * rmin;   // == max_j w_j
        c1[b] = m * iv * L2E;
        c0[b] = -mx * L2E;
        ek[b] = __builtin_amdgcn_exp2f(__builtin_fmaf(rkk * iv, L2E, c0[b]));
        se[b] = 0.f; dp[b] = 0.f;
    }

    const float4* lp = clP + k;

    // ---- pass 2: exp + weighted dot, 2 j per iter ----
#pragma unroll 4
    for (int jp = 0; jp < 128; ++jp) {
        float4 cl = lp[(size_t)jp * 256];       // {c0, l0, c1, l1}
        float4 om0 = omI[2 * jp];
        float4 om1 = omI[2 * jp + 1];
        float4 va0 = vaI[2 * jp];
        float4 va1 = vaI[2 * jp + 1];
        float o0[4] = {om0.x, om0.y, om0.z, om0.w};
        float o1[4] = {om1.x, om1.y, om1.z, om1.w};
        float v0[4] = {va0.x, va0.y, va0.z, va0.w};
        float v1[4] = {va1.x, va1.y, va1.z, va1.w};
#pragma unroll
        for (int b = 0; b < NB; ++b) {
            float p0 = cl.x * o0[b];
            float e0 = __builtin_amdgcn_exp2f(__builtin_fmaf(p0, c1[b], c0[b]));
            float p1 = cl.z * o1[b];
            float e1 = __builtin_amdgcn_exp2f(__builtin_fmaf(p1, c1[b], c0[b]));
            se[b] += e0 + e1;
            dp[b]  = __builtin_fmaf(e0, cl.y * v0[b], dp[b]);
            dp[b]  = __builtin_fmaf(e1, cl.w * v1[b], dp[b]);
        }
    }

    // ---- epilogue: swap spurious diag exp for the true one ----
#pragma unroll
    for (int b = 0; b < NB; ++b) {
        float espur = __builtin_amdgcn_exp2f(c0[b]);
        float sef = se[b] + (ek[b] - espur);
        float dpf = __builtin_fmaf(ek[b], ldiag * vak[b], dp[b]);
        out[(size_t)(b0 + b) * 256 + k] = dpf * __builtin_amdgcn_rcpf(sef);
    }
}

extern "C" void kernel_launch(void* const* d_in, const int* in_sizes, int n_in,
                              void* d_out, int out_size, void* d_ws, size_t ws_size,
                              hipStream_t stream) {
    const float* x    = (const float*)d_in[0];   // [4096,2,1024]
    const float* W    = (const float*)d_in[1];   // [256,1024]
    const float* cov  = (const float*)d_in[2];   // [256,256]
    const float* ldng = (const float*)d_in[3];   // [256,256]
    float* out = (float*)d_out;                  // [4096,256]

    // ws footprint identical to the R9-proven 8.83 MB layout
    float*  C    = (float*)d_ws;                         // [8192,256]
    float*  wsum = C + (size_t)8192 * 256;               // [256]
    float2* covP = (float2*)(wsum + 256);                // [128*256] pairs
    float4* clP  = (float4*)((float*)covP + 65536);      // [128*256] quads

    wsum_kernel<<<64, 256, 0, stream>>>(W, wsum);
    prep_kernel<<<dim3(8, 8), 256, 0, stream>>>(cov, ldng, covP, clP);
    gemm_kernel<<<dim3(128, 4), 256, 0, stream>>>(x, W, C);
    head_kernel<<<1024, 256, 0, stream>>>(C, wsum, covP, clP, cov, ldng, out);
}